// Round 1
// baseline (864.087 us; speedup 1.0000x reference)
//
#include <hip/hip_runtime.h>
#include <hip/hip_bf16.h>

typedef unsigned short u16;
typedef unsigned int u32;
typedef __attribute__((ext_vector_type(8))) short short8;   // bf16x8 MFMA frag (4 VGPR)
typedef __attribute__((ext_vector_type(4))) float float4v;  // fp32x4 acc
typedef __attribute__((ext_vector_type(4))) unsigned int uint4v; // 16B vector

__device__ __forceinline__ u16 f2bf(float f) {
    union { float f; unsigned int u; } v; v.f = f;
    unsigned int r = v.u + 0x7fffu + ((v.u >> 16) & 1u);  // RNE
    return (u16)(r >> 16);
}

// packed fp32x2 -> bf16x2 (no builtin on gfx950; T12 recipe)
__device__ __forceinline__ u32 cvtpk(float lo, float hi) {
    u32 r;
    asm("v_cvt_pk_bf16_f32 %0, %1, %2" : "=v"(r) : "v"(lo), "v"(hi));
    return r;
}

// async 16B global -> LDS (lane i lands at ldsbase + i*16)
__device__ __forceinline__ void gld_lds16(const u16* g, u16* l) {
    __builtin_amdgcn_global_load_lds(
        (const __attribute__((address_space(1))) u32*)g,
        (__attribute__((address_space(3))) u32*)l, 16, 0, 0);
}

// ---------------------------------------------------------------------------
// x: fp32 [8192*1024] -> bf16. 8 elements/thread.
// ---------------------------------------------------------------------------
__global__ __launch_bounds__(256) void convert_x(
    const float* __restrict__ x, u16* __restrict__ xb) {
    int i = (blockIdx.x * 256 + threadIdx.x) * 8;
    float4v a = *(const float4v*)&x[i];
    float4v b = *(const float4v*)&x[i + 4];
    u16 tmp[8] __attribute__((aligned(16)));
#pragma unroll
    for (int j = 0; j < 4; ++j) { tmp[j] = f2bf(a[j]); tmp[4 + j] = f2bf(b[j]); }
    *(uint4v*)&xb[i] = *(uint4v*)tmp;
}

// ---------------------------------------------------------------------------
// Weight transpose+convert: W fp32 [1024][1024] (K x N) -> Wt bf16 (N x K).
// ---------------------------------------------------------------------------
__global__ __launch_bounds__(256) void transpose_w(
    const float* __restrict__ w0, const float* __restrict__ w1,
    const float* __restrict__ w2, const float* __restrict__ w3,
    u16* __restrict__ o0, u16* __restrict__ o1,
    u16* __restrict__ o2, u16* __restrict__ o3) {
    __shared__ u16 t[32][33];
    int z = blockIdx.z;
    const float* w = (z == 0) ? w0 : (z == 1) ? w1 : (z == 2) ? w2 : w3;
    u16* o         = (z == 0) ? o0 : (z == 1) ? o1 : (z == 2) ? o2 : o3;
    int bx = blockIdx.x * 32;   // input col (n)
    int by = blockIdx.y * 32;   // input row (k)
    int x = threadIdx.x, y = threadIdx.y;   // block (32,8)
#pragma unroll
    for (int i = 0; i < 4; ++i)
        t[y + i * 8][x] = f2bf(w[(size_t)(by + y + i * 8) * 1024 + bx + x]);
    __syncthreads();
#pragma unroll
    for (int i = 0; i < 4; ++i)
        o[(size_t)(bx + y + i * 8) * 1024 + by + x] = t[x][y + i * 8];
}

// ---------------------------------------------------------------------------
// GEMM: C[M][N] = A[M][K] @ Bt[N][K]^T, bf16 in, fp32 accum.
// mode 0: bf16 out, scaled by oscale (folds softmax scale into Q proj)
// mode 1: bf16 out, transposed [b*1024+f][2048] (V)
// mode 2: fp32 out (final projection)
// ---------------------------------------------------------------------------
__global__ __launch_bounds__(256) void gemm_bt(
    const u16* __restrict__ A, const u16* __restrict__ Bt,
    void* __restrict__ Cout, int M, int N, int K, int mode, float oscale) {
    __shared__ __attribute__((aligned(16))) u16 As[128 * 32];
    __shared__ __attribute__((aligned(16))) u16 Bs[128 * 32];
    const int tid = threadIdx.x;
    const int m0 = blockIdx.y * 128;
    const int n0 = blockIdx.x * 128;
    const int wid = tid >> 6;
    const int lane = tid & 63;
    const int ln = lane & 15, kq = lane >> 4;
    const int wm = (wid >> 1) * 64, wn = (wid & 1) * 64;

    float4v acc[4][4] = {};
    for (int k0 = 0; k0 < K; k0 += 32) {
#pragma unroll
        for (int i = 0; i < 2; ++i) {
            int chunk = tid + i * 256;          // 16B chunk id, 0..511
            int row = chunk >> 2, cg = chunk & 3;
            u16* lA = &As[(size_t)(i * 256 + wid * 64) * 8];
            u16* lB = &Bs[(size_t)(i * 256 + wid * 64) * 8];
            gld_lds16(&A[(size_t)(m0 + row) * K + k0 + cg * 8], lA);
            gld_lds16(&Bt[(size_t)(n0 + row) * K + k0 + cg * 8], lB);
        }
        __syncthreads();
        short8 af[4], bfr[4];
#pragma unroll
        for (int mt = 0; mt < 4; ++mt)
            af[mt] = *(const short8*)&As[(wm + mt * 16 + ln) * 32 + kq * 8];
#pragma unroll
        for (int nt = 0; nt < 4; ++nt)
            bfr[nt] = *(const short8*)&Bs[(wn + nt * 16 + ln) * 32 + kq * 8];
#pragma unroll
        for (int mt = 0; mt < 4; ++mt)
#pragma unroll
            for (int nt = 0; nt < 4; ++nt)
                acc[mt][nt] = __builtin_amdgcn_mfma_f32_16x16x32_bf16(
                    af[mt], bfr[nt], acc[mt][nt], 0, 0, 0);
        __syncthreads();
    }
    if (mode == 0) {
        u16* C = (u16*)Cout;
#pragma unroll
        for (int mt = 0; mt < 4; ++mt)
#pragma unroll
            for (int nt = 0; nt < 4; ++nt)
#pragma unroll
                for (int r = 0; r < 4; ++r) {
                    int row = m0 + wm + mt * 16 + kq * 4 + r;
                    int col = n0 + wn + nt * 16 + ln;
                    C[(size_t)row * N + col] = f2bf(acc[mt][nt][r] * oscale);
                }
    } else if (mode == 1) {
        u16* C = (u16*)Cout;
#pragma unroll
        for (int mt = 0; mt < 4; ++mt)
#pragma unroll
            for (int nt = 0; nt < 4; ++nt)
#pragma unroll
                for (int r = 0; r < 4; ++r) {
                    int t = m0 + wm + mt * 16 + kq * 4 + r;
                    int col = n0 + wn + nt * 16 + ln;
                    int b = t >> 11, n = t & 2047;
                    C[((size_t)(b * 1024 + col)) * 2048 + n] = f2bf(acc[mt][nt][r]);
                }
    } else {
        float* C = (float*)Cout;
#pragma unroll
        for (int mt = 0; mt < 4; ++mt)
#pragma unroll
            for (int nt = 0; nt < 4; ++nt)
#pragma unroll
                for (int r = 0; r < 4; ++r) {
                    int row = m0 + wm + mt * 16 + kq * 4 + r;
                    int col = n0 + wn + nt * 16 + ln;
                    C[(size_t)row * N + col] = acc[mt][nt][r];
                }
    }
}

// ---------------------------------------------------------------------------
// Fused attention, head-axis softmax.  R6 rewrite:
//  * q-tile 32 -> 16, grid 512 blocks, LDS 76 KB, VGPR capped 64
//    -> 2 blocks/CU: two independent barrier groups overlap stalls.
//  * E kept fp32 in LDS (no bf16 pack/unpack on store, Di sum, rescale).
//  * Swapped QK^T (mfma(K,Q) -> S^T): lane holds 4 consecutive k -> the
//    E-store is one ds_write_b128 of the float4 accumulator per nt.
//  * Row stride 36 dwords: 16B-aligned b128s, uniform bank spread.
//  * Softmax scale pre-folded into Q projection (exp path = min + v_exp).
//  * A-frag built with 4x v_cvt_pk_bf16_f32 (only bf16 conversion left).
// Barriers: 2 per k-tile; E ping-pong buffer last touched 2 barriers ago.
// qb/cb alias -- block reads its own 16 Q rows before writing same rows.
// ---------------------------------------------------------------------------
__global__ __launch_bounds__(1024, 8) void attn_kernel(
    const u16* qb, const u16* __restrict__ kb,
    const u16* __restrict__ vt, u16* cb) {
    // rows = h*16+q (256 rows), cols k 0..31, stride 36 fp32
    __shared__ __attribute__((aligned(16))) float Ef[2][256 * 36]; // 73728 B
    __shared__ __attribute__((aligned(16))) float Di[16 * 36];     //  2304 B

    const int b = blockIdx.y;
    const int q0 = blockIdx.x * 16;
    const int tid = threadIdx.x;
    const int wid = tid >> 6, lane = tid & 63;   // wid 0..15 = head
    const int ln = lane & 15, kq = lane >> 4;
    const int h = wid;

    // Preload Q fragments (already scaled by 0.125*log2e in the Q GEMM)
    short8 aq[2];
#pragma unroll
    for (int kc = 0; kc < 2; ++kc)
        aq[kc] = *(const short8*)&qb[
            (size_t)(b * 2048 + q0 + ln) * 1024 + h * 64 + kc * 32 + kq * 8];

    float4v cacc[4] = {};   // [nt] ctx accumulators (16q x 64d)

#pragma unroll 1
    for (int kt = 0; kt < 2048; kt += 32) {
        const int cur = (kt >> 5) & 1;
        float* E = Ef[cur];

        // ---- S^T = K @ Q^T for this head (C: col=q=ln, row=k=kq*4+r)
        short8 bk[2][2];   // [kc][nt]
#pragma unroll
        for (int kc = 0; kc < 2; ++kc)
#pragma unroll
            for (int nt = 0; nt < 2; ++nt)
                bk[kc][nt] = *(const short8*)&kb[
                    (size_t)(b * 2048 + kt + nt * 16 + ln) * 1024 +
                    h * 64 + kc * 32 + kq * 8];

        float4v sacc[2] = {};   // [nt]
#pragma unroll
        for (int kc = 0; kc < 2; ++kc)
#pragma unroll
            for (int nt = 0; nt < 2; ++nt)
                sacc[nt] = __builtin_amdgcn_mfma_f32_16x16x32_bf16(
                    bk[kc][nt], aq[kc], sacc[nt], 0, 0, 0);

        // ---- E = exp2(S) fp32, one b128 store per nt (4 consecutive k)
#pragma unroll
        for (int nt = 0; nt < 2; ++nt) {
            float4v e;
#pragma unroll
            for (int r = 0; r < 4; ++r)
                e[r] = exp2f(fminf(sacc[nt][r], 115.0f));
            *(float4v*)&E[(h * 16 + ln) * 36 + nt * 16 + kq * 4] = e;
        }

        // ---- hoisted V gather (consumed after BAR-B; hides global latency)
        short8 bv[4];
#pragma unroll
        for (int nt = 0; nt < 4; ++nt)
            bv[nt] = *(const short8*)&vt[
                (size_t)(b * 1024 + h * 64 + nt * 16 + ln) * 2048 + kt + kq * 8];

        __syncthreads();   // BAR-A: E[cur] complete

        // ---- Dinv = 1 / sum_h E  (512 threads, one (q,k) each, fp32 reads)
        if (tid < 512) {
            const int q = tid >> 5, kk = tid & 31;
            const float* ec = &E[q * 36 + kk];
            float d0 = 0.f, d1 = 0.f, d2 = 0.f, d3 = 0.f;
#pragma unroll
            for (int hh = 0; hh < 4; ++hh) {
                d0 += ec[(hh * 4 + 0) * (16 * 36)];
                d1 += ec[(hh * 4 + 1) * (16 * 36)];
                d2 += ec[(hh * 4 + 2) * (16 * 36)];
                d3 += ec[(hh * 4 + 3) * (16 * 36)];
            }
            Di[q * 36 + kk] = __builtin_amdgcn_rcpf((d0 + d1) + (d2 + d3));
        }
        __syncthreads();   // BAR-B: Di complete

        // ---- A-frag = (E * Dinv) packed bf16 via cvt_pk; ctx += A @ V
        const float* ep = &E[(h * 16 + ln) * 36 + kq * 8];
        const float* dp = &Di[ln * 36 + kq * 8];
        float4v e0 = *(const float4v*)&ep[0];
        float4v e1 = *(const float4v*)&ep[4];
        float4v g0 = *(const float4v*)&dp[0];
        float4v g1 = *(const float4v*)&dp[4];
        u32 pk[4] __attribute__((aligned(16)));
        pk[0] = cvtpk(e0[0] * g0[0], e0[1] * g0[1]);
        pk[1] = cvtpk(e0[2] * g0[2], e0[3] * g0[3]);
        pk[2] = cvtpk(e1[0] * g1[0], e1[1] * g1[1]);
        pk[3] = cvtpk(e1[2] * g1[2], e1[3] * g1[3]);
        short8 ap = *(short8*)pk;
#pragma unroll
        for (int nt = 0; nt < 4; ++nt)
            cacc[nt] = __builtin_amdgcn_mfma_f32_16x16x32_bf16(
                ap, bv[nt], cacc[nt], 0, 0, 0);
    }

    // Epilogue: ctx[b*2048+q][h*64+d], bf16  (cb aliases qb -- same rows only)
#pragma unroll
    for (int nt = 0; nt < 4; ++nt)
#pragma unroll
        for (int r = 0; r < 4; ++r) {
            int row = b * 2048 + q0 + kq * 4 + r;
            int col = h * 64 + nt * 16 + ln;
            cb[(size_t)row * 1024 + col] = f2bf(cacc[nt][r]);
        }
}

// ---------------------------------------------------------------------------
extern "C" void kernel_launch(void* const* d_in, const int* in_sizes, int n_in,
                              void* d_out, int out_size, void* d_ws, size_t ws_size,
                              hipStream_t stream) {
    const float* x   = (const float*)d_in[0];   // [8192][1024] fp32
    const float* w_q = (const float*)d_in[1];   // [1024][1024] fp32 (K x N)
    const float* w_k = (const float*)d_in[2];
    const float* w_v = (const float*)d_in[3];
    const float* w_o = (const float*)d_in[4];

    char* ws = (char*)d_ws;
    const size_t SZ_W   = (size_t)1024 * 1024 * 2;   // 2 MiB
    const size_t SZ_TOK = (size_t)8192 * 1024 * 2;   // 16 MiB
    // ws layout (40 MiB): x_bf | wtq wtk wtv wto | q_buf(=ctx)
    u16* x_bf  = (u16*)(ws);
    u16* wtq   = (u16*)(ws + SZ_TOK);
    u16* wtk   = (u16*)(ws + SZ_TOK + SZ_W);
    u16* wtv   = (u16*)(ws + SZ_TOK + 2 * SZ_W);
    u16* wto   = (u16*)(ws + SZ_TOK + 3 * SZ_W);
    u16* q_buf = (u16*)(ws + SZ_TOK + 4 * SZ_W);     // also ctx (aliased)
    // k_buf / vt_buf live in d_out (32 MiB fp32) -- dead before final GEMM writes it
    u16* k_buf  = (u16*)d_out;
    u16* vt_buf = (u16*)d_out + (size_t)8192 * 1024;

    // 0. convert x to bf16
    convert_x<<<4096, 256, 0, stream>>>(x, x_bf);

    // 1. transpose+convert weights to Bt (N x K) bf16 layout
    transpose_w<<<dim3(32, 32, 4), dim3(32, 8), 0, stream>>>(
        w_q, w_k, w_v, w_o, wtq, wtk, wtv, wto);

    // 2. QKV projections (Q pre-scaled by 0.125*log2e for exp2-domain scores;
    //    V written directly in transposed [b*1024+f][2048] layout)
    gemm_bt<<<dim3(8, 64), 256, 0, stream>>>(x_bf, wtq, q_buf, 8192, 1024, 1024, 0, 0.18033688f);
    gemm_bt<<<dim3(8, 64), 256, 0, stream>>>(x_bf, wtk, k_buf, 8192, 1024, 1024, 0, 1.0f);
    gemm_bt<<<dim3(8, 64), 256, 0, stream>>>(x_bf, wtv, vt_buf, 8192, 1024, 1024, 1, 1.0f);

    // 3. fused attention with head-axis softmax (ctx written into q_buf)
    attn_kernel<<<dim3(128, 4), 1024, 0, stream>>>(q_buf, k_buf, vt_buf, q_buf);

    // 4. output projection -> fp32 d_out (overwrites k_buf/vt_buf scratch)
    gemm_bt<<<dim3(8, 64), 256, 0, stream>>>(q_buf, wto, d_out, 8192, 1024, 1024, 2, 1.0f);
}

// Round 2
// 494.392 us; speedup vs baseline: 1.7478x; 1.7478x over previous
//
#include <hip/hip_runtime.h>
#include <hip/hip_bf16.h>

typedef unsigned short u16;
typedef unsigned int u32;
typedef __attribute__((ext_vector_type(8))) short short8;   // bf16x8 MFMA frag (4 VGPR)
typedef __attribute__((ext_vector_type(4))) float float4v;  // fp32x4 acc
typedef __attribute__((ext_vector_type(4))) unsigned int uint4v; // 16B vector

__device__ __forceinline__ u16 f2bf(float f) {
    union { float f; unsigned int u; } v; v.f = f;
    unsigned int r = v.u + 0x7fffu + ((v.u >> 16) & 1u);  // RNE
    return (u16)(r >> 16);
}

// packed fp32x2 -> bf16x2 (no builtin on gfx950; T12 recipe)
__device__ __forceinline__ u32 cvtpk(float lo, float hi) {
    u32 r;
    asm("v_cvt_pk_bf16_f32 %0, %1, %2" : "=v"(r) : "v"(lo), "v"(hi));
    return r;
}

// async 16B global -> LDS (lane i lands at ldsbase + i*16)
__device__ __forceinline__ void gld_lds16(const u16* g, u16* l) {
    __builtin_amdgcn_global_load_lds(
        (const __attribute__((address_space(1))) u32*)g,
        (__attribute__((address_space(3))) u32*)l, 16, 0, 0);
}

// ---------------------------------------------------------------------------
// x: fp32 [8192*1024] -> bf16. 8 elements/thread.
// ---------------------------------------------------------------------------
__global__ __launch_bounds__(256) void convert_x(
    const float* __restrict__ x, u16* __restrict__ xb) {
    int i = (blockIdx.x * 256 + threadIdx.x) * 8;
    float4v a = *(const float4v*)&x[i];
    float4v b = *(const float4v*)&x[i + 4];
    u16 tmp[8] __attribute__((aligned(16)));
#pragma unroll
    for (int j = 0; j < 4; ++j) { tmp[j] = f2bf(a[j]); tmp[4 + j] = f2bf(b[j]); }
    *(uint4v*)&xb[i] = *(uint4v*)tmp;
}

// ---------------------------------------------------------------------------
// Weight transpose+convert: W fp32 [1024][1024] (K x N) -> Wt bf16 (N x K).
// ---------------------------------------------------------------------------
__global__ __launch_bounds__(256) void transpose_w(
    const float* __restrict__ w0, const float* __restrict__ w1,
    const float* __restrict__ w2, const float* __restrict__ w3,
    u16* __restrict__ o0, u16* __restrict__ o1,
    u16* __restrict__ o2, u16* __restrict__ o3) {
    __shared__ u16 t[32][33];
    int z = blockIdx.z;
    const float* w = (z == 0) ? w0 : (z == 1) ? w1 : (z == 2) ? w2 : w3;
    u16* o         = (z == 0) ? o0 : (z == 1) ? o1 : (z == 2) ? o2 : o3;
    int bx = blockIdx.x * 32;   // input col (n)
    int by = blockIdx.y * 32;   // input row (k)
    int x = threadIdx.x, y = threadIdx.y;   // block (32,8)
#pragma unroll
    for (int i = 0; i < 4; ++i)
        t[y + i * 8][x] = f2bf(w[(size_t)(by + y + i * 8) * 1024 + bx + x]);
    __syncthreads();
#pragma unroll
    for (int i = 0; i < 4; ++i)
        o[(size_t)(bx + y + i * 8) * 1024 + by + x] = t[x][y + i * 8];
}

// ---------------------------------------------------------------------------
// GEMM: C[M][N] = A[M][K] @ Bt[N][K]^T, bf16 in, fp32 accum.
// mode 0: bf16 out, scaled by oscale (folds softmax scale into Q proj)
// mode 1: bf16 out, transposed [b*1024+f][2048] (V)
// mode 2: fp32 out (final projection)
// ---------------------------------------------------------------------------
__global__ __launch_bounds__(256) void gemm_bt(
    const u16* __restrict__ A, const u16* __restrict__ Bt,
    void* __restrict__ Cout, int M, int N, int K, int mode, float oscale) {
    __shared__ __attribute__((aligned(16))) u16 As[128 * 32];
    __shared__ __attribute__((aligned(16))) u16 Bs[128 * 32];
    const int tid = threadIdx.x;
    const int m0 = blockIdx.y * 128;
    const int n0 = blockIdx.x * 128;
    const int wid = tid >> 6;
    const int lane = tid & 63;
    const int ln = lane & 15, kq = lane >> 4;
    const int wm = (wid >> 1) * 64, wn = (wid & 1) * 64;

    float4v acc[4][4] = {};
    for (int k0 = 0; k0 < K; k0 += 32) {
#pragma unroll
        for (int i = 0; i < 2; ++i) {
            int chunk = tid + i * 256;          // 16B chunk id, 0..511
            int row = chunk >> 2, cg = chunk & 3;
            u16* lA = &As[(size_t)(i * 256 + wid * 64) * 8];
            u16* lB = &Bs[(size_t)(i * 256 + wid * 64) * 8];
            gld_lds16(&A[(size_t)(m0 + row) * K + k0 + cg * 8], lA);
            gld_lds16(&Bt[(size_t)(n0 + row) * K + k0 + cg * 8], lB);
        }
        __syncthreads();
        short8 af[4], bfr[4];
#pragma unroll
        for (int mt = 0; mt < 4; ++mt)
            af[mt] = *(const short8*)&As[(wm + mt * 16 + ln) * 32 + kq * 8];
#pragma unroll
        for (int nt = 0; nt < 4; ++nt)
            bfr[nt] = *(const short8*)&Bs[(wn + nt * 16 + ln) * 32 + kq * 8];
#pragma unroll
        for (int mt = 0; mt < 4; ++mt)
#pragma unroll
            for (int nt = 0; nt < 4; ++nt)
                acc[mt][nt] = __builtin_amdgcn_mfma_f32_16x16x32_bf16(
                    af[mt], bfr[nt], acc[mt][nt], 0, 0, 0);
        __syncthreads();
    }
    if (mode == 0) {
        u16* C = (u16*)Cout;
#pragma unroll
        for (int mt = 0; mt < 4; ++mt)
#pragma unroll
            for (int nt = 0; nt < 4; ++nt)
#pragma unroll
                for (int r = 0; r < 4; ++r) {
                    int row = m0 + wm + mt * 16 + kq * 4 + r;
                    int col = n0 + wn + nt * 16 + ln;
                    C[(size_t)row * N + col] = f2bf(acc[mt][nt][r] * oscale);
                }
    } else if (mode == 1) {
        u16* C = (u16*)Cout;
#pragma unroll
        for (int mt = 0; mt < 4; ++mt)
#pragma unroll
            for (int nt = 0; nt < 4; ++nt)
#pragma unroll
                for (int r = 0; r < 4; ++r) {
                    int t = m0 + wm + mt * 16 + kq * 4 + r;
                    int col = n0 + wn + nt * 16 + ln;
                    int b = t >> 11, n = t & 2047;
                    C[((size_t)(b * 1024 + col)) * 2048 + n] = f2bf(acc[mt][nt][r]);
                }
    } else {
        float* C = (float*)Cout;
#pragma unroll
        for (int mt = 0; mt < 4; ++mt)
#pragma unroll
            for (int nt = 0; nt < 4; ++nt)
#pragma unroll
                for (int r = 0; r < 4; ++r) {
                    int row = m0 + wm + mt * 16 + kq * 4 + r;
                    int col = n0 + wn + nt * 16 + ln;
                    C[(size_t)row * N + col] = acc[mt][nt][r];
                }
    }
}

// ---------------------------------------------------------------------------
// Fused attention, head-axis softmax.  R7 = R5 shape + R6 structure:
//  * q-tile 32, grid (64,4), 1024 thr (1 head/wave), 1 block/CU (LDS-bound).
//  * NO forced min-waves: R6's (1024,8) capped VGPR at 32 -> 240 MB scratch
//    spills (WRITE_SIZE counter).  Plain __launch_bounds__(1024) gives the
//    allocator 128 VGPR -- enough for aq(16)+cacc(32)+bv(16)+temps.
//  * E kept fp32 in LDS (no bf16 pack/unpack on store, Di sum, rescale).
//  * Swapped QK^T (mfma(K,Q) -> S^T): lane holds 4 consecutive k -> the
//    E-store is one ds_write_b128 of the float4 accumulator per (mt,nt).
//  * Row stride 36 dwords: all b128 phases hit the 8-cycle wave floor
//    (8 lanes per 4-bank group), no net conflicts.
//  * Softmax scale pre-folded into Q projection (exp path = min + v_exp).
//  * A-frag built with 4x v_cvt_pk_bf16_f32 per mt.
// Barriers: 2 per k-tile; E ping-pong buffer last touched 2 barriers ago.
// LDS = 2*73728 (E) + 4608 (Di) = 152064 B.
// qb/cb alias -- block reads its own 32 Q rows before writing same rows.
// ---------------------------------------------------------------------------
__global__ __launch_bounds__(1024) void attn_kernel(
    const u16* qb, const u16* __restrict__ kb,
    const u16* __restrict__ vt, u16* cb) {
    // rows = h*32+q (512 rows), cols k 0..31, stride 36 fp32
    __shared__ __attribute__((aligned(16))) float Ef[2][512 * 36]; // 147456 B
    __shared__ __attribute__((aligned(16))) float Di[32 * 36];     //   4608 B

    const int b = blockIdx.y;
    const int q0 = blockIdx.x * 32;
    const int tid = threadIdx.x;
    const int wid = tid >> 6, lane = tid & 63;   // wid 0..15 = head
    const int ln = lane & 15, kq = lane >> 4;
    const int h = wid;

    // Preload Q fragments (already scaled by 0.125*log2e in the Q GEMM)
    short8 aq[2][2];   // [mt][kc]
#pragma unroll
    for (int mt = 0; mt < 2; ++mt)
#pragma unroll
        for (int kc = 0; kc < 2; ++kc)
            aq[mt][kc] = *(const short8*)&qb[
                (size_t)(b * 2048 + q0 + mt * 16 + ln) * 1024 +
                h * 64 + kc * 32 + kq * 8];

    float4v cacc[2][4] = {};   // [mt][nt] ctx accumulators (32q x 64d)

#pragma unroll 1
    for (int kt = 0; kt < 2048; kt += 32) {
        const int cur = (kt >> 5) & 1;
        float* E = Ef[cur];

        // ---- S^T = K @ Q^T for this head (C: col=q=ln, row=k=kq*4+r)
        short8 bk[2][2];   // [kc][nt]
#pragma unroll
        for (int kc = 0; kc < 2; ++kc)
#pragma unroll
            for (int nt = 0; nt < 2; ++nt)
                bk[kc][nt] = *(const short8*)&kb[
                    (size_t)(b * 2048 + kt + nt * 16 + ln) * 1024 +
                    h * 64 + kc * 32 + kq * 8];

        float4v sacc[2][2] = {};   // [mt][nt]
#pragma unroll
        for (int kc = 0; kc < 2; ++kc)
#pragma unroll
            for (int mt = 0; mt < 2; ++mt)
#pragma unroll
                for (int nt = 0; nt < 2; ++nt)
                    sacc[mt][nt] = __builtin_amdgcn_mfma_f32_16x16x32_bf16(
                        bk[kc][nt], aq[mt][kc], sacc[mt][nt], 0, 0, 0);

        // ---- E = exp2(S) fp32, one b128 store per (mt,nt)
#pragma unroll
        for (int mt = 0; mt < 2; ++mt)
#pragma unroll
            for (int nt = 0; nt < 2; ++nt) {
                float4v e;
#pragma unroll
                for (int r = 0; r < 4; ++r)
                    e[r] = exp2f(fminf(sacc[mt][nt][r], 115.0f));
                *(float4v*)&E[(h * 32 + mt * 16 + ln) * 36 + nt * 16 + kq * 4] = e;
            }

        // ---- hoisted V gather (consumed after BAR-B; hides global latency)
        short8 bv[4];
#pragma unroll
        for (int nt = 0; nt < 4; ++nt)
            bv[nt] = *(const short8*)&vt[
                (size_t)(b * 1024 + h * 64 + nt * 16 + ln) * 2048 + kt + kq * 8];

        __syncthreads();   // BAR-A: E[cur] complete

        // ---- Dinv = 1 / sum_h E  (1024 threads, one (q,k) pair each)
        {
            const int q = tid >> 5, kk = tid & 31;
            const float* ec = &E[q * 36 + kk];
            float d0 = 0.f, d1 = 0.f, d2 = 0.f, d3 = 0.f;
#pragma unroll
            for (int hh = 0; hh < 4; ++hh) {
                d0 += ec[(hh * 4 + 0) * (32 * 36)];
                d1 += ec[(hh * 4 + 1) * (32 * 36)];
                d2 += ec[(hh * 4 + 2) * (32 * 36)];
                d3 += ec[(hh * 4 + 3) * (32 * 36)];
            }
            Di[q * 36 + kk] = __builtin_amdgcn_rcpf((d0 + d1) + (d2 + d3));
        }
        __syncthreads();   // BAR-B: Di complete

        // ---- A-frag = (E * Dinv) packed bf16 via cvt_pk; ctx += A @ V
        short8 ap[2];
#pragma unroll
        for (int mt = 0; mt < 2; ++mt) {
            const float* ep = &E[(h * 32 + mt * 16 + ln) * 36 + kq * 8];
            const float* dp = &Di[(mt * 16 + ln) * 36 + kq * 8];
            float4v e0 = *(const float4v*)&ep[0];
            float4v e1 = *(const float4v*)&ep[4];
            float4v g0 = *(const float4v*)&dp[0];
            float4v g1 = *(const float4v*)&dp[4];
            u32 pk[4] __attribute__((aligned(16)));
            pk[0] = cvtpk(e0[0] * g0[0], e0[1] * g0[1]);
            pk[1] = cvtpk(e0[2] * g0[2], e0[3] * g0[3]);
            pk[2] = cvtpk(e1[0] * g1[0], e1[1] * g1[1]);
            pk[3] = cvtpk(e1[2] * g1[2], e1[3] * g1[3]);
            ap[mt] = *(short8*)pk;
        }
#pragma unroll
        for (int nt = 0; nt < 4; ++nt)
#pragma unroll
            for (int mt = 0; mt < 2; ++mt)
                cacc[mt][nt] = __builtin_amdgcn_mfma_f32_16x16x32_bf16(
                    ap[mt], bv[nt], cacc[mt][nt], 0, 0, 0);
    }

    // Epilogue: ctx[b*2048+q][h*64+d], bf16  (cb aliases qb -- same rows only)
#pragma unroll
    for (int mt = 0; mt < 2; ++mt)
#pragma unroll
        for (int nt = 0; nt < 4; ++nt)
#pragma unroll
            for (int r = 0; r < 4; ++r) {
                int row = b * 2048 + q0 + mt * 16 + kq * 4 + r;
                int col = h * 64 + nt * 16 + ln;
                cb[(size_t)row * 1024 + col] = f2bf(cacc[mt][nt][r]);
            }
}

// ---------------------------------------------------------------------------
extern "C" void kernel_launch(void* const* d_in, const int* in_sizes, int n_in,
                              void* d_out, int out_size, void* d_ws, size_t ws_size,
                              hipStream_t stream) {
    const float* x   = (const float*)d_in[0];   // [8192][1024] fp32
    const float* w_q = (const float*)d_in[1];   // [1024][1024] fp32 (K x N)
    const float* w_k = (const float*)d_in[2];
    const float* w_v = (const float*)d_in[3];
    const float* w_o = (const float*)d_in[4];

    char* ws = (char*)d_ws;
    const size_t SZ_W   = (size_t)1024 * 1024 * 2;   // 2 MiB
    const size_t SZ_TOK = (size_t)8192 * 1024 * 2;   // 16 MiB
    // ws layout (40 MiB): x_bf | wtq wtk wtv wto | q_buf(=ctx)
    u16* x_bf  = (u16*)(ws);
    u16* wtq   = (u16*)(ws + SZ_TOK);
    u16* wtk   = (u16*)(ws + SZ_TOK + SZ_W);
    u16* wtv   = (u16*)(ws + SZ_TOK + 2 * SZ_W);
    u16* wto   = (u16*)(ws + SZ_TOK + 3 * SZ_W);
    u16* q_buf = (u16*)(ws + SZ_TOK + 4 * SZ_W);     // also ctx (aliased)
    // k_buf / vt_buf live in d_out (32 MiB fp32) -- dead before final GEMM writes it
    u16* k_buf  = (u16*)d_out;
    u16* vt_buf = (u16*)d_out + (size_t)8192 * 1024;

    // 0. convert x to bf16
    convert_x<<<4096, 256, 0, stream>>>(x, x_bf);

    // 1. transpose+convert weights to Bt (N x K) bf16 layout
    transpose_w<<<dim3(32, 32, 4), dim3(32, 8), 0, stream>>>(
        w_q, w_k, w_v, w_o, wtq, wtk, wtv, wto);

    // 2. QKV projections (Q pre-scaled by 0.125*log2e for exp2-domain scores;
    //    V written directly in transposed [b*1024+f][2048] layout)
    gemm_bt<<<dim3(8, 64), 256, 0, stream>>>(x_bf, wtq, q_buf, 8192, 1024, 1024, 0, 0.18033688f);
    gemm_bt<<<dim3(8, 64), 256, 0, stream>>>(x_bf, wtk, k_buf, 8192, 1024, 1024, 0, 1.0f);
    gemm_bt<<<dim3(8, 64), 256, 0, stream>>>(x_bf, wtv, vt_buf, 8192, 1024, 1024, 1, 1.0f);

    // 3. fused attention with head-axis softmax (ctx written into q_buf)
    attn_kernel<<<dim3(64, 4), 1024, 0, stream>>>(q_buf, k_buf, vt_buf, q_buf);

    // 4. output projection -> fp32 d_out (overwrites k_buf/vt_buf scratch)
    gemm_bt<<<dim3(8, 64), 256, 0, stream>>>(q_buf, wto, d_out, 8192, 1024, 1024, 2, 1.0f);
}